// Round 1
// 320.807 us; speedup vs baseline: 1.4138x; 1.4138x over previous
//
#include <hip/hip_runtime.h>
#include <math.h>

#define L0T 365
#define L1T 366
#define LT  732
#define NTILE 46
#define NW   4
#define NTHR 256
#define PI_F 3.14159265358979323846f

typedef short svec8 __attribute__((ext_vector_type(8)));   // 8 bf16
typedef float fvec4 __attribute__((ext_vector_type(4)));
typedef float fvec16 __attribute__((ext_vector_type(16)));
typedef unsigned uvec4 __attribute__((ext_vector_type(4)));

__device__ __forceinline__ unsigned short f2bf(float f) {
    unsigned u = __float_as_uint(f);
    u = (u + 0x7fffu + ((u >> 16) & 1u)) >> 16;
    return (unsigned short)u;
}
__device__ __forceinline__ float bf2f(unsigned short s) {
    return __uint_as_float(((unsigned)s) << 16);
}
__device__ __forceinline__ unsigned pk2(float a, float b) {
    return (unsigned)f2bf(a) | ((unsigned)f2bf(b) << 16);
}
// packed RNE f32->bf16x2 (same rounding as f2bf), 1 instruction for 2 values
__device__ __forceinline__ unsigned cvtpk(float a, float b) {
    unsigned r;
    asm("v_cvt_pk_bf16_f32 %0, %1, %2" : "=v"(r) : "v"(a), "v"(b));
    return r;
}
__device__ __forceinline__ float pgetv(uvec4 p, int j) {
    unsigned u = p[j >> 1];
    return bf2f((unsigned short)((j & 1) ? (u >> 16) : (u & 0xffffu)));
}
__device__ __forceinline__ svec8 pack8(float4 a, float4 c) {
    uvec4 u;
    u[0] = cvtpk(a.x, a.y); u[1] = cvtpk(a.z, a.w);
    u[2] = cvtpk(c.x, c.y); u[3] = cvtpk(c.z, c.w);
    return __builtin_bit_cast(svec8, u);
}

// One 2-layer embed MLP evaluation for the wave's 16-token tile.
// Weight tables are pre-arranged in LANE ORDER: [2 frag][64 lane][8 bf16]
// so each frag load is ds_read_b128 at lane*16B (conflict-free).
// Biases are folded into the MFMA C operand.
__device__ __forceinline__ void embed_pass(
    const unsigned short* __restrict__ T1,
    const unsigned short* __restrict__ T2,
    const float* __restrict__ Bh, const float* __restrict__ Bx,
    svec8 bx, int ln, int Q, float* __restrict__ out)
{
    svec8 w1f0 = *(const svec8*)&T1[ln * 8];
    svec8 w1f1 = *(const svec8*)&T1[512 + ln * 8];
    const fvec4* bh = (const fvec4*)&Bh[Q * 8];
    fvec4 d0 = __builtin_amdgcn_mfma_f32_16x16x32_bf16(w1f0, bx, bh[0], 0, 0, 0);
    fvec4 d1 = __builtin_amdgcn_mfma_f32_16x16x32_bf16(w1f1, bx, bh[1], 0, 0, 0);
    uvec4 hu;
    hu[0] = cvtpk(fmaxf(d0[0], 0.f), fmaxf(d0[1], 0.f));
    hu[1] = cvtpk(fmaxf(d0[2], 0.f), fmaxf(d0[3], 0.f));
    hu[2] = cvtpk(fmaxf(d1[0], 0.f), fmaxf(d1[1], 0.f));
    hu[3] = cvtpk(fmaxf(d1[2], 0.f), fmaxf(d1[3], 0.f));
    svec8 hf = __builtin_bit_cast(svec8, hu);
    svec8 w2f0 = *(const svec8*)&T2[ln * 8];
    svec8 w2f1 = *(const svec8*)&T2[512 + ln * 8];
    const fvec4* bb = (const fvec4*)&Bx[Q * 8];
    fvec4 g0 = __builtin_amdgcn_mfma_f32_16x16x32_bf16(w2f0, hf, bb[0], 0, 0, 0);
    fvec4 g1 = __builtin_amdgcn_mfma_f32_16x16x32_bf16(w2f1, hf, bb[1], 0, 0, 0);
    out[0] = g0[0]; out[1] = g0[1]; out[2] = g0[2]; out[3] = g0[3];
    out[4] = g1[0]; out[5] = g1[1]; out[6] = g1[2]; out[7] = g1[3];
}

// Full embed (incl. posenc + set selection) for tile t. Produces this lane's
// x values: feats Q*8+j of token t*16+tk. Invalid tokens (>731) produce 0.
__device__ __forceinline__ void embed_tile(
    int t, int b, int tk, int Q, int ln,
    const float* __restrict__ x0, const float* __restrict__ x1,
    const float* __restrict__ pos0, const float* __restrict__ pos1,
    const float* __restrict__ xcT,
    const unsigned short* __restrict__ TBL,
    const float* __restrict__ BIA,
    const float* __restrict__ PWl,
    float* __restrict__ xv)
{
    const int tok = t * 16 + tk;
    if (t < 22) {                       // all 16 tokens are x0-valid
        svec8 bx;
        #pragma unroll
        for (int j = 0; j < 8; j++) bx[j] = 0;
        if (Q == 0) {
            const float4* px = (const float4*)(x0 + ((size_t)b * L0T + tok) * 8);
            bx = pack8(px[0], px[1]);
        }
        embed_pass(TBL, TBL + 1024, BIA, BIA + 32, bx, ln, Q, xv);
        float pv = pos0[(size_t)b * L0T + tok];
        #pragma unroll
        for (int j = 0; j < 8; j += 2) {
            float s, c; __sincosf(pv * PWl[j], &s, &c);
            xv[j] += s; xv[j + 1] += c;
        }
    } else if (t == 22) {               // boundary tile: tokens 352..367
        float ea[8], eb[8];
        svec8 bx0, bx1;
        #pragma unroll
        for (int j = 0; j < 8; j++) { bx0[j] = 0; bx1[j] = 0; }
        if (Q == 0 && tok < L0T) {
            const float4* px = (const float4*)(x0 + ((size_t)b * L0T + tok) * 8);
            bx0 = pack8(px[0], px[1]);
        }
        if (Q < 2 && tok >= L0T) {
            const float4* px = (const float4*)(x1 + ((size_t)b * L1T + (tok - L0T)) * 16 + Q * 8);
            bx1 = pack8(px[0], px[1]);
        }
        embed_pass(TBL,        TBL + 1024, BIA,      BIA + 32, bx0, ln, Q, ea);
        embed_pass(TBL + 2048, TBL + 3072, BIA + 64, BIA + 96, bx1, ln, Q, eb);
        float pv = (tok < L0T) ? pos0[(size_t)b * L0T + tok]
                               : pos1[(size_t)b * L1T + (tok - L0T)];
        #pragma unroll
        for (int j = 0; j < 8; j += 2) {
            float s, c; __sincosf(pv * PWl[j], &s, &c);
            xv[j]     = ((tok < L0T) ? ea[j]     : eb[j])     + s;
            xv[j + 1] = ((tok < L0T) ? ea[j + 1] : eb[j + 1]) + c;
        }
    } else if (t < 45) {                // all 16 tokens are x1-valid
        svec8 bx;
        #pragma unroll
        for (int j = 0; j < 8; j++) bx[j] = 0;
        if (Q < 2) {
            const float4* px = (const float4*)(x1 + ((size_t)b * L1T + (tok - L0T)) * 16 + Q * 8);
            bx = pack8(px[0], px[1]);
        }
        embed_pass(TBL + 2048, TBL + 3072, BIA + 64, BIA + 96, bx, ln, Q, xv);
        float pv = pos1[(size_t)b * L1T + (tok - L0T)];
        #pragma unroll
        for (int j = 0; j < 8; j += 2) {
            float s, c; __sincosf(pv * PWl[j], &s, &c);
            xv[j] += s; xv[j + 1] += c;
        }
    } else {                            // t == 45: tokens 720..730 x1, 731 xc, rest 0
        float ea[8], eb[8];
        svec8 bx1, bxc;
        #pragma unroll
        for (int j = 0; j < 8; j++) bx1[j] = 0;
        if (Q < 2 && tok <= LT - 2) {
            const float4* px = (const float4*)(x1 + ((size_t)b * L1T + (tok - L0T)) * 16 + Q * 8);
            bx1 = pack8(px[0], px[1]);
        }
        {
            const float4* px = (const float4*)(xcT + (size_t)b * 32 + Q * 8);
            bxc = pack8(px[0], px[1]);
        }
        embed_pass(TBL + 2048, TBL + 3072, BIA + 64,  BIA + 96,  bx1, ln, Q, ea);
        embed_pass(TBL + 4096, TBL + 5120, BIA + 128, BIA + 160, bxc, ln, Q, eb);
        float pv = (tok <= LT - 2) ? pos1[(size_t)b * L1T + (tok - L0T)] : 0.f;
        #pragma unroll
        for (int j = 0; j < 8; j += 2) {
            float s, c; __sincosf(pv * PWl[j], &s, &c);
            xv[j]     = (tok <= LT - 2) ? ea[j] + s     : ((tok == LT - 1) ? eb[j]     : 0.f);
            xv[j + 1] = (tok <= LT - 2) ? ea[j + 1] + c : ((tok == LT - 1) ? eb[j + 1] : 0.f);
        }
    }
}

__global__ __launch_bounds__(NTHR, 6) void fused_kernel(
    const float* __restrict__ x0,  const float* __restrict__ x1,
    const float* __restrict__ pos0,const float* __restrict__ pos1,
    const float* __restrict__ xcT,
    const float* __restrict__ e0w1,const float* __restrict__ e0b1,
    const float* __restrict__ e0w2,const float* __restrict__ e0b2,
    const float* __restrict__ e1w1,const float* __restrict__ e1b1,
    const float* __restrict__ e1w2,const float* __restrict__ e1b2,
    const float* __restrict__ ecw1,const float* __restrict__ ecb1,
    const float* __restrict__ ecw2,const float* __restrict__ ecb2,
    const float* __restrict__ wq,  const float* __restrict__ wk,
    const float* __restrict__ wv,  const float* __restrict__ wo,
    const float* __restrict__ ln1g,const float* __restrict__ ln1b,
    const float* __restrict__ ln2g,const float* __restrict__ ln2b,
    const float* __restrict__ f1w1,const float* __restrict__ f1b1,
    const float* __restrict__ f1w2,const float* __restrict__ f1b2,
    const float* __restrict__ f2w1,const float* __restrict__ f2b1,
    const float* __restrict__ f2w2,const float* __restrict__ f2b2,
    float* __restrict__ out)
{
    const int b   = blockIdx.x;
    const int tid = threadIdx.x;
    const int w   = tid >> 6;          // wave 0..3
    const int ln  = tid & 63;
    const int tk  = ln & 15;
    const int Q   = ln >> 4;
    const int Lr0 = ((tk >> 2) * 8) + (tk & 3);
    const int Lr1 = Lr0 + 4;

    // LDS: ~24.0 KB total -> 6 WGs/CU
    __shared__ unsigned short TBL[6 * 1024] __attribute__((aligned(16))); // 12288 B
    __shared__ float BIA[192] __attribute__((aligned(16)));               //   768 B
    __shared__ unsigned PCK[128] __attribute__((aligned(16)));            //   512 B
    __shared__ float PW[32] __attribute__((aligned(16)));                 //   128 B
    __shared__ float T1f[1024] __attribute__((aligned(16)));              //  4096 B (aliases gram staging)
    __shared__ float CmT2[1024] __attribute__((aligned(16)));             //  4096 B (Cm, then T2f)
    __shared__ unsigned short Wbb[1024] __attribute__((aligned(16)));     //  2048 B
    __shared__ float red[NW * 3];

    // ================= Phase 0: build bf16 weight tables (lane-order) =====
    for (int idx = tid; idx < 1024; idx += NTHR) {
        int f = idx >> 9, lane = (idx >> 3) & 63, j = idx & 7;
        int tkk = lane & 15, QQ = lane >> 4;
        int Lr = ((tkk >> 2) * 8) + (tkk & 3) + f * 4;
        int col = QQ * 8 + j;
        TBL[idx]        = (col < 8)  ? f2bf(e0w1[Lr * 8  + col]) : (unsigned short)0;
        TBL[1024 + idx] = f2bf(e0w2[Lr * 32 + col]);
        TBL[2048 + idx] = (col < 16) ? f2bf(e1w1[Lr * 16 + col]) : (unsigned short)0;
        TBL[3072 + idx] = f2bf(e1w2[Lr * 32 + col]);
        TBL[4096 + idx] = f2bf(ecw1[Lr * 32 + col]);
        TBL[5120 + idx] = f2bf(ecw2[Lr * 32 + col]);
        CmT2[idx] = 0.f;
    }
    if (tid < 192) {
        int s = tid >> 5, i = tid & 31;
        float bv;
        if      (s == 0) bv = e0b1[i];
        else if (s == 1) bv = e0b2[i];
        else if (s == 2) bv = e1b1[i];
        else if (s == 3) bv = e1b2[i];
        else if (s == 4) bv = ecb1[i];
        else             bv = ecb2[i];
        BIA[tid] = bv;
    }
    if (tid < 128) {
        int t8 = tid >> 4, q = (tid >> 2) & 3, i = tid & 3, f = q * 8 + 2 * i;
        const float* sp;
        if      (t8 == 0) sp = ln1g;
        else if (t8 == 1) sp = ln1b;
        else if (t8 == 2) sp = ln2g;
        else if (t8 == 3) sp = ln2b;
        else if (t8 == 4) sp = f1b1;
        else if (t8 == 5) sp = f1b2;
        else if (t8 == 6) sp = f2b1;
        else              sp = f2w2;
        PCK[tid] = pk2(sp[f], sp[f + 1]);
    }
    if (tid < 32) {
        int q = tid >> 3, j = tid & 7;
        PW[tid] = PI_F / (float)(q * 4 + (j >> 1) + 1);
    }
    __syncthreads();

    const float* PWl = &PW[Q * 8];

    // ================= Phase 1: embed + Gram (streamed, per-wave staging) ==
    {
        unsigned short* ST = (unsigned short*)T1f;   // [4 waves][16 tok][32 feat]
        const int feat = ln & 31, half = ln >> 5;
        fvec16 dG;
        #pragma unroll
        for (int i = 0; i < 16; i++) dG[i] = 0.f;
        for (int t = w; t < NTILE; t += NW) {
            float xv[8];
            embed_tile(t, b, tk, Q, ln, x0, x1, pos0, pos1, xcT, TBL, BIA, PWl, xv);
            uvec4 pk;
            pk[0] = cvtpk(xv[0], xv[1]); pk[1] = cvtpk(xv[2], xv[3]);
            pk[2] = cvtpk(xv[4], xv[5]); pk[3] = cvtpk(xv[6], xv[7]);
            *(uvec4*)&ST[(w * 16 + tk) * 32 + Q * 8] = pk;   // b128, conflict-free
            svec8 af;                                         // transpose read
            #pragma unroll
            for (int j = 0; j < 8; j++)
                af[j] = (short)ST[w * 512 + (half * 8 + j) * 32 + feat];
            dG = __builtin_amdgcn_mfma_f32_32x32x16_bf16(af, af, dG, 0, 0, 0);
        }
        #pragma unroll
        for (int rg = 0; rg < 16; rg++) {
            int row = (rg & 3) + 8 * (rg >> 2) + 4 * half;
            atomicAdd(&CmT2[row * 32 + feat], dG[rg]);
        }
    }
    __syncthreads();

    // ================= Phase 2: attention collapse =========================
    for (int idx = tid; idx < 1024; idx += NTHR) {       // T1 = Cm * wk^T
        int i = idx >> 5, g = idx & 31;
        const float4* cr = (const float4*)&CmT2[i * 32];
        const float4* wr = (const float4*)&wk[g * 32];
        float a = 0.f;
        #pragma unroll
        for (int j4 = 0; j4 < 8; j4++) {
            float4 cc = cr[j4], ww = wr[j4];
            a = fmaf(cc.x, ww.x, a); a = fmaf(cc.y, ww.y, a);
            a = fmaf(cc.z, ww.z, a); a = fmaf(cc.w, ww.w, a);
        }
        T1f[idx] = a;
    }
    __syncthreads();
    const float rsL = rsqrtf((float)LT);
    for (int idx = tid; idx < 1024; idx += NTHR) {       // T2 = wq * T1 (scaled)
        int h = idx >> 5, g = idx & 31;
        const float4* qr = (const float4*)&wq[h * 32];
        float a = 0.f;
        #pragma unroll
        for (int i4 = 0; i4 < 8; i4++) {
            float4 qq = qr[i4];
            a = fmaf(qq.x, T1f[(i4 * 4 + 0) * 32 + g], a);
            a = fmaf(qq.y, T1f[(i4 * 4 + 1) * 32 + g], a);
            a = fmaf(qq.z, T1f[(i4 * 4 + 2) * 32 + g], a);
            a = fmaf(qq.w, T1f[(i4 * 4 + 3) * 32 + g], a);
        }
        CmT2[idx] = a * rsL;
    }
    __syncthreads();
    {   // row softmax, 8 threads per row (was serial tid<32)
        int r = tid >> 3, c0 = (tid & 7) * 4;
        float4 vv = *(const float4*)&CmT2[r * 32 + c0];
        float m = fmaxf(fmaxf(vv.x, vv.y), fmaxf(vv.z, vv.w));
        m = fmaxf(m, __shfl_xor(m, 1));
        m = fmaxf(m, __shfl_xor(m, 2));
        m = fmaxf(m, __shfl_xor(m, 4));
        float ex = __expf(vv.x - m), ey = __expf(vv.y - m);
        float ez = __expf(vv.z - m), ew = __expf(vv.w - m);
        float s = ex + ey + ez + ew;
        s += __shfl_xor(s, 1); s += __shfl_xor(s, 2); s += __shfl_xor(s, 4);
        float inv = 1.f / s;
        float4 o; o.x = ex * inv; o.y = ey * inv; o.z = ez * inv; o.w = ew * inv;
        *(float4*)&CmT2[r * 32 + c0] = o;
    }
    __syncthreads();
    for (int idx = tid; idx < 1024; idx += NTHR) {       // T1 = att * wv
        int h = idx >> 5, j = idx & 31;
        const float4* pr = (const float4*)&CmT2[h * 32];
        float a = 0.f;
        #pragma unroll
        for (int g4 = 0; g4 < 8; g4++) {
            float4 pp = pr[g4];
            a = fmaf(pp.x, wv[(g4 * 4 + 0) * 32 + j], a);
            a = fmaf(pp.y, wv[(g4 * 4 + 1) * 32 + j], a);
            a = fmaf(pp.z, wv[(g4 * 4 + 2) * 32 + j], a);
            a = fmaf(pp.w, wv[(g4 * 4 + 3) * 32 + j], a);
        }
        T1f[idx] = a;
    }
    __syncthreads();
    for (int idx = tid; idx < 1024; idx += NTHR) {       // Wb = wo * T1 + I
        int o = idx >> 5, j = idx & 31;
        const float4* orow = (const float4*)&wo[o * 32];
        float a = 0.f;
        #pragma unroll
        for (int h4 = 0; h4 < 8; h4++) {
            float4 oo = orow[h4];
            a = fmaf(oo.x, T1f[(h4 * 4 + 0) * 32 + j], a);
            a = fmaf(oo.y, T1f[(h4 * 4 + 1) * 32 + j], a);
            a = fmaf(oo.z, T1f[(h4 * 4 + 2) * 32 + j], a);
            a = fmaf(oo.w, T1f[(h4 * 4 + 3) * 32 + j], a);
        }
        Wbb[idx] = f2bf(a + (o == j ? 1.f : 0.f));
    }
    __syncthreads();

    // ================= Phase 3: pipeline (embed recomputed per tile) =======
    svec8 wbf0 = *(const svec8*)&Wbb[Lr0 * 32 + Q * 8];
    svec8 wbf1 = *(const svec8*)&Wbb[Lr1 * 32 + Q * 8];
    svec8 a1f0, a1f1, a2f0, a2f1, a3f0, a3f1;
    #pragma unroll
    for (int j = 0; j < 8; j++) {
        a1f0[j] = (short)f2bf(f1w1[Lr0 * 32 + Q * 8 + j]);
        a1f1[j] = (short)f2bf(f1w1[Lr1 * 32 + Q * 8 + j]);
        a2f0[j] = (short)f2bf(f1w2[Lr0 * 32 + Q * 8 + j]);
        a2f1[j] = (short)f2bf(f1w2[Lr1 * 32 + Q * 8 + j]);
        a3f0[j] = (short)f2bf(f2w1[Lr0 * 32 + Q * 8 + j]);
        a3f1[j] = (short)f2bf(f2w1[Lr1 * 32 + Q * 8 + j]);
    }
    const float ybias = f2b2[0];
    const fvec4 zc = {0.f, 0.f, 0.f, 0.f};

    float s0 = 0.f, s1 = 0.f, s2 = 0.f;
    for (int t = w; t < NTILE; t += NW) {
        float xv[8];
        embed_tile(t, b, tk, Q, ln, x0, x1, pos0, pos1, xcT, TBL, BIA, PWl, xv);
        uvec4 pkx;
        pkx[0] = cvtpk(xv[0], xv[1]); pkx[1] = cvtpk(xv[2], xv[3]);
        pkx[2] = cvtpk(xv[4], xv[5]); pkx[3] = cvtpk(xv[6], xv[7]);
        svec8 bx = __builtin_bit_cast(svec8, pkx);

        const uvec4* P4 = (const uvec4*)PCK;      // broadcast LDS reads
        uvec4 pg1 = P4[Q],      pb1 = P4[4 + Q];
        uvec4 pg2 = P4[8 + Q],  pb2 = P4[12 + Q];
        uvec4 pc1 = P4[16 + Q], pc2 = P4[20 + Q];
        uvec4 pc3 = P4[24 + Q], pw2 = P4[28 + Q];

        fvec4 d0 = __builtin_amdgcn_mfma_f32_16x16x32_bf16(wbf0, bx, zc, 0, 0, 0);
        fvec4 d1 = __builtin_amdgcn_mfma_f32_16x16x32_bf16(wbf1, bx, zc, 0, 0, 0);
        float v[8];
        #pragma unroll
        for (int j = 0; j < 4; j++) { v[j] = d0[j]; v[4 + j] = d1[j]; }
        float S = 0.f;
        #pragma unroll
        for (int j = 0; j < 8; j++) S += v[j];
        S += __shfl_xor(S, 16); S += __shfl_xor(S, 32);
        float mean = S * (1.f / 32.f);
        float vs = 0.f;
        #pragma unroll
        for (int j = 0; j < 8; j++) { float d = v[j] - mean; vs = fmaf(d, d, vs); }
        vs += __shfl_xor(vs, 16); vs += __shfl_xor(vs, 32);
        float rs = rsqrtf(vs * (1.f / 32.f) + 1e-5f);
        float n[8];
        #pragma unroll
        for (int j = 0; j < 8; j++)
            n[j] = (v[j] - mean) * rs * pgetv(pg1, j) + pgetv(pb1, j);
        uvec4 tu;
        tu[0] = cvtpk(n[0], n[1]); tu[1] = cvtpk(n[2], n[3]);
        tu[2] = cvtpk(n[4], n[5]); tu[3] = cvtpk(n[6], n[7]);
        svec8 tf = __builtin_bit_cast(svec8, tu);
        fvec4 u0 = __builtin_amdgcn_mfma_f32_16x16x32_bf16(a1f0, tf, zc, 0, 0, 0);
        fvec4 u1 = __builtin_amdgcn_mfma_f32_16x16x32_bf16(a1f1, tf, zc, 0, 0, 0);
        uvec4 uu;
        uu[0] = cvtpk(fmaxf(u0[0] + pgetv(pc1, 0), 0.f), fmaxf(u0[1] + pgetv(pc1, 1), 0.f));
        uu[1] = cvtpk(fmaxf(u0[2] + pgetv(pc1, 2), 0.f), fmaxf(u0[3] + pgetv(pc1, 3), 0.f));
        uu[2] = cvtpk(fmaxf(u1[0] + pgetv(pc1, 4), 0.f), fmaxf(u1[1] + pgetv(pc1, 5), 0.f));
        uu[3] = cvtpk(fmaxf(u1[2] + pgetv(pc1, 6), 0.f), fmaxf(u1[3] + pgetv(pc1, 7), 0.f));
        svec8 uf = __builtin_bit_cast(svec8, uu);
        fvec4 g0 = __builtin_amdgcn_mfma_f32_16x16x32_bf16(a2f0, uf, zc, 0, 0, 0);
        fvec4 g1 = __builtin_amdgcn_mfma_f32_16x16x32_bf16(a2f1, uf, zc, 0, 0, 0);
        #pragma unroll
        for (int j = 0; j < 8; j++)
            v[j] = (j < 4 ? g0[j] : g1[j - 4]) + pgetv(pc2, j) + xv[j];
        float S2 = 0.f;
        #pragma unroll
        for (int j = 0; j < 8; j++) S2 += v[j];
        S2 += __shfl_xor(S2, 16); S2 += __shfl_xor(S2, 32);
        float mean2 = S2 * (1.f / 32.f);
        float vs2 = 0.f;
        #pragma unroll
        for (int j = 0; j < 8; j++) { float d = v[j] - mean2; vs2 = fmaf(d, d, vs2); }
        vs2 += __shfl_xor(vs2, 16); vs2 += __shfl_xor(vs2, 32);
        float rs2 = rsqrtf(vs2 * (1.f / 32.f) + 1e-5f);
        float n2[8];
        #pragma unroll
        for (int j = 0; j < 8; j++)
            n2[j] = (v[j] - mean2) * rs2 * pgetv(pg2, j) + pgetv(pb2, j);
        uvec4 t2u;
        t2u[0] = cvtpk(n2[0], n2[1]); t2u[1] = cvtpk(n2[2], n2[3]);
        t2u[2] = cvtpk(n2[4], n2[5]); t2u[3] = cvtpk(n2[6], n2[7]);
        svec8 t2 = __builtin_bit_cast(svec8, t2u);
        fvec4 q0 = __builtin_amdgcn_mfma_f32_16x16x32_bf16(a3f0, t2, zc, 0, 0, 0);
        fvec4 q1 = __builtin_amdgcn_mfma_f32_16x16x32_bf16(a3f1, t2, zc, 0, 0, 0);
        float yp = 0.f;
        #pragma unroll
        for (int j = 0; j < 8; j++) {
            float e = (j < 4 ? q0[j] : q1[j - 4]) + pgetv(pc3, j);
            yp = fmaf(pgetv(pw2, j), fmaxf(e, 0.f), yp);
        }
        yp += __shfl_xor(yp, 16); yp += __shfl_xor(yp, 32);
        if (Q == 0) {
            int tok = t * 16 + tk;
            float yv = yp + ybias;
            if (tok < L0T)            s0 += yv;
            else if (tok < LT - 1)    s1 += yv;
            else if (tok == LT - 1)   s2 += yv;
        }
    }

    s0 += __shfl_xor(s0, 1); s0 += __shfl_xor(s0, 2);
    s0 += __shfl_xor(s0, 4); s0 += __shfl_xor(s0, 8);
    s1 += __shfl_xor(s1, 1); s1 += __shfl_xor(s1, 2);
    s1 += __shfl_xor(s1, 4); s1 += __shfl_xor(s1, 8);
    s2 += __shfl_xor(s2, 1); s2 += __shfl_xor(s2, 2);
    s2 += __shfl_xor(s2, 4); s2 += __shfl_xor(s2, 8);
    if (ln == 0) { red[w * 3] = s0; red[w * 3 + 1] = s1; red[w * 3 + 2] = s2; }
    __syncthreads();
    if (tid == 0) {
        float a0 = 0.f, a1 = 0.f, a2 = 0.f;
        #pragma unroll
        for (int k = 0; k < NW; k++) {
            a0 += red[k * 3]; a1 += red[k * 3 + 1]; a2 += red[k * 3 + 2];
        }
        out[b] = a0 / (float)L0T + a1 / (float)L1T + a2;
    }
}

extern "C" void kernel_launch(void* const* d_in, const int* in_sizes, int n_in,
                              void* d_out, int out_size, void* d_ws, size_t ws_size,
                              hipStream_t stream)
{
    const float* x0   = (const float*)d_in[0];
    const float* x1   = (const float*)d_in[1];
    const float* pos0 = (const float*)d_in[2];
    const float* pos1 = (const float*)d_in[3];
    const float* xcT  = (const float*)d_in[4];
    const float* e0w1 = (const float*)d_in[5];
    const float* e0b1 = (const float*)d_in[6];
    const float* e0w2 = (const float*)d_in[7];
    const float* e0b2 = (const float*)d_in[8];
    const float* e1w1 = (const float*)d_in[9];
    const float* e1b1 = (const float*)d_in[10];
    const float* e1w2 = (const float*)d_in[11];
    const float* e1b2 = (const float*)d_in[12];
    const float* ecw1 = (const float*)d_in[13];
    const float* ecb1 = (const float*)d_in[14];
    const float* ecw2 = (const float*)d_in[15];
    const float* ecb2 = (const float*)d_in[16];
    const float* wq   = (const float*)d_in[17];
    const float* wk   = (const float*)d_in[18];
    const float* wv   = (const float*)d_in[19];
    const float* wo   = (const float*)d_in[20];
    const float* ln1g = (const float*)d_in[21];
    const float* ln1b = (const float*)d_in[22];
    const float* ln2g = (const float*)d_in[23];
    const float* ln2b = (const float*)d_in[24];
    const float* f1w1 = (const float*)d_in[25];
    const float* f1b1 = (const float*)d_in[26];
    const float* f1w2 = (const float*)d_in[27];
    const float* f1b2 = (const float*)d_in[28];
    const float* f2w1 = (const float*)d_in[29];
    const float* f2b1 = (const float*)d_in[30];
    const float* f2w2 = (const float*)d_in[31];
    const float* f2b2 = (const float*)d_in[32];
    float* out = (float*)d_out;

    const int B = in_sizes[0] / (L0T * 8);

    hipLaunchKernelGGL(fused_kernel, dim3(B), dim3(NTHR), 0, stream,
                       x0, x1, pos0, pos1, xcT,
                       e0w1, e0b1, e0w2, e0b2, e1w1, e1b1, e1w2, e1b2,
                       ecw1, ecb1, ecw2, ecb2, wq, wk, wv, wo,
                       ln1g, ln1b, ln2g, ln2b,
                       f1w1, f1b1, f1w2, f1b2, f2w1, f2b1, f2w2, f2b2,
                       out);
}